// Round 9
// baseline (1551.221 us; speedup 1.0000x reference)
//
#include <hip/hip_runtime.h>
#include <hip/hip_fp16.h>

#define HID 6
#define HS  8                   // padded row stride (floats) for h buffers
#define NUM_GRAPHS 1000
#define BSHIFT 10
#define BNODES (1 << BSHIFT)    // 1024 nodes per bucket
#define MAXNB 1024              // max buckets
#define P1_CHUNK 3072
#define P1_PERT  12             // P1_CHUNK / 256

__device__ __forceinline__ unsigned pk2(float a, float b) {
    __half2 h = __floats2half2_rn(a, b);
    return *(unsigned*)&h;
}
__device__ __forceinline__ float2 up2(unsigned u) {
    __half2 h = *(__half2*)&u;
    return __half22float2(h);
}

// ===========================================================================
// pad x (N x 6) -> hX (N x 8)
// ===========================================================================
__global__ void pad_kernel(const float* __restrict__ x, float* __restrict__ hX, int N) {
    int i = blockIdx.x * blockDim.x + threadIdx.x;
    if (i >= N) return;
    const float2* s = (const float2*)(x + (size_t)i * HID);
    float2 a = s[0], b = s[1], c = s[2];
    float4* o = (float4*)(hX + (size_t)i * HS);
    o[0] = make_float4(a.x, a.y, b.x, b.y);
    o[1] = make_float4(c.x, c.y, 0.f, 0.f);
}

__global__ void init_gcursor_kernel(int* __restrict__ gcursor, int NB, int cap) {
    int b = blockIdx.x * blockDim.x + threadIdx.x;
    if (b < NB) gcursor[b] = b * cap;
}

// ===========================================================================
// pass1: bin edges by dst>>BSHIFT into fixed-capacity bucket regions.
// Coalesced reads AND writes via LDS permute of 16B packed records.
// ===========================================================================
__global__ void __launch_bounds__(256) pass1_kernel(
        const int* __restrict__ src, const int* __restrict__ dst,
        const float* __restrict__ ea,
        int* __restrict__ gcursor,
        uint4* __restrict__ packed_perm,
        int E, int cap, int NB) {
    __shared__ uint4 pay[P1_CHUNK];                  // 48 KB
    __shared__ int hist[MAXNB];                      // 4 KB (reused as rank cnt)
    __shared__ int base[MAXNB];                      // 4 KB
    __shared__ int lofs[MAXNB];                      // 4 KB
    __shared__ int pairs[256];                       // 1 KB

    int t = threadIdx.x;
    long e0 = (long)blockIdx.x * P1_CHUNK;
    long rem = (long)E - e0;
    int count = (int)(rem < P1_CHUNK ? rem : P1_CHUNK);

    for (int b = t; b < MAXNB; b += 256) hist[b] = 0;
    __syncthreads();

    // phase 1: histogram (dst kept in registers)
    int d[P1_PERT];
#pragma unroll
    for (int j = 0; j < P1_PERT; ++j) {
        int le = t + j * 256;
        d[j] = (le < count) ? dst[e0 + le] : -1;
        if (d[j] >= 0) atomicAdd(&hist[d[j] >> BSHIFT], 1);
    }
    __syncthreads();

    // phase 2a: exclusive scan of hist[0..MAXNB) -> lofs (4 buckets/thread)
    {
        int b0 = 4 * t;
        int s0 = hist[b0], s1 = hist[b0 + 1], s2 = hist[b0 + 2], s3 = hist[b0 + 3];
        pairs[t] = s0 + s1 + s2 + s3;
        __syncthreads();
        for (int off = 1; off < 256; off <<= 1) {
            int a = (t >= off) ? pairs[t - off] : 0;
            __syncthreads();
            pairs[t] += a;
            __syncthreads();
        }
        int excl = (t == 0) ? 0 : pairs[t - 1];
        lofs[b0] = excl;
        lofs[b0 + 1] = excl + s0;
        lofs[b0 + 2] = excl + s0 + s1;
        lofs[b0 + 3] = excl + s0 + s1 + s2;
    }
    __syncthreads();
    // phase 2b: reserve global space per touched bucket (reads hist)
    for (int b = t; b < NB; b += 256) {
        int c = hist[b];
        base[b] = c ? atomicAdd(&gcursor[b], c) : 0;
    }
    __syncthreads();
    // reuse hist as per-bucket rank counter
    for (int b = t; b < MAXNB; b += 256) hist[b] = 0;
    __syncthreads();

    // phase 3: coalesced payload read -> pack fp16 -> LDS scatter at slot
#pragma unroll
    for (int j = 0; j < P1_PERT; ++j) {
        int le = t + j * 256;
        if (le >= count) continue;
        int dd = d[j];
        int b = dd >> BSHIFT;
        long e = e0 + le;
        int s = src[e];
        const float2* ep = (const float2*)(ea + (size_t)e * HID);
        float2 A = ep[0], B = ep[1], C = ep[2];
        uint4 p;
        p.x = pk2(A.x, A.y);
        p.y = pk2(B.x, B.y);
        p.z = pk2(C.x, C.y);
        p.w = (unsigned)s | ((unsigned)(dd & (BNODES - 1)) << 20);
        int r = atomicAdd(&hist[b], 1);
        pay[lofs[b] + r] = p;
    }
    __syncthreads();

    // phase 4: sequential LDS read -> contiguous global runs.
    // bucket of slot found by binary search in lofs (ascending).
    for (int s2 = t; s2 < count; s2 += 256) {
        int lo = 0, hi = NB - 1;
        while (lo < hi) {
            int mid = (lo + hi + 1) >> 1;
            if (lofs[mid] <= s2) lo = mid; else hi = mid - 1;
        }
        long gpos = (long)base[lo] + (s2 - lofs[lo]);
        packed_perm[gpos] = pay[s2];
    }
}

// ===========================================================================
// bucket-fused GINE layer: one WG per 1024-node bucket; LDS agg; 4x batched
// edge loop for memory-level parallelism; coalesced epilogue.
// ===========================================================================
__global__ void __launch_bounds__(256) layer_kernel(
        const float* __restrict__ h,
        const uint4* __restrict__ packed,
        const int* __restrict__ gcursor,
        const float* __restrict__ W, const float* __restrict__ b,
        float* __restrict__ out, int N, int cap, int do_relu) {
    __shared__ float sagg[BNODES * HID];     // 24 KB
    __shared__ float sW[HID * HID];
    __shared__ float sb[HID];
    int t = threadIdx.x;
    int bk = blockIdx.x;
    if (t < HID * HID) sW[t] = W[t];
    if (t < HID) sb[t] = b[t];
    for (int i = t; i < BNODES * HID; i += 256) sagg[i] = 0.f;
    __syncthreads();

    long kbeg = (long)bk * cap;
    int cnt = gcursor[bk] - (int)kbeg;

#define EDGE_UPD(P, G0, G1)                                                   \
    do {                                                                      \
        int dl_ = (P.w >> 20) & (BNODES - 1);                                 \
        float2 e01 = up2(P.x), e23 = up2(P.y), e45 = up2(P.z);                \
        float* pp = sagg + (size_t)dl_ * HID;                                 \
        atomicAdd(pp + 0, fmaxf(G0.x + e01.x, 0.f));                          \
        atomicAdd(pp + 1, fmaxf(G0.y + e01.y, 0.f));                          \
        atomicAdd(pp + 2, fmaxf(G0.z + e23.x, 0.f));                          \
        atomicAdd(pp + 3, fmaxf(G0.w + e23.y, 0.f));                          \
        atomicAdd(pp + 4, fmaxf(G1.x + e45.x, 0.f));                          \
        atomicAdd(pp + 5, fmaxf(G1.y + e45.y, 0.f));                          \
    } while (0)

    int k4 = cnt & ~(4 * 256 - 1);
    for (int k = t; k < k4; k += 4 * 256) {
        uint4 p0 = packed[kbeg + k];
        uint4 p1 = packed[kbeg + k + 256];
        uint4 p2 = packed[kbeg + k + 512];
        uint4 p3 = packed[kbeg + k + 768];
        int s0 = p0.w & 0xFFFFF, s1 = p1.w & 0xFFFFF;
        int s2 = p2.w & 0xFFFFF, s3 = p3.w & 0xFFFFF;
        float4 a0 = *(const float4*)(h + (size_t)s0 * HS);
        float4 b0 = *(const float4*)(h + (size_t)s0 * HS + 4);
        float4 a1 = *(const float4*)(h + (size_t)s1 * HS);
        float4 b1 = *(const float4*)(h + (size_t)s1 * HS + 4);
        float4 a2 = *(const float4*)(h + (size_t)s2 * HS);
        float4 b2 = *(const float4*)(h + (size_t)s2 * HS + 4);
        float4 a3 = *(const float4*)(h + (size_t)s3 * HS);
        float4 b3 = *(const float4*)(h + (size_t)s3 * HS + 4);
        EDGE_UPD(p0, a0, b0);
        EDGE_UPD(p1, a1, b1);
        EDGE_UPD(p2, a2, b2);
        EDGE_UPD(p3, a3, b3);
    }
    for (int k = k4 + t; k < cnt; k += 256) {
        uint4 p = packed[kbeg + k];
        int s = p.w & 0xFFFFF;
        float4 g0 = *(const float4*)(h + (size_t)s * HS);
        float4 g1 = *(const float4*)(h + (size_t)s * HS + 4);
        EDGE_UPD(p, g0, g1);
    }
#undef EDGE_UPD
    __syncthreads();

    int nodeBase = bk << BSHIFT;
    for (int n = t; n < BNODES; n += 256) {
        int i = nodeBase + n;
        if (i >= N) break;
        float4 h0 = *(const float4*)(h + (size_t)i * HS);
        float4 h1 = *(const float4*)(h + (size_t)i * HS + 4);
        const float* sp = sagg + (size_t)n * HID;
        float tv[HID];
        tv[0] = h0.x + sp[0]; tv[1] = h0.y + sp[1]; tv[2] = h0.z + sp[2];
        tv[3] = h0.w + sp[3]; tv[4] = h1.x + sp[4]; tv[5] = h1.y + sp[5];
        float o[HID];
#pragma unroll
        for (int dd = 0; dd < HID; ++dd) o[dd] = sb[dd];
#pragma unroll
        for (int k = 0; k < HID; ++k)
#pragma unroll
            for (int dd = 0; dd < HID; ++dd) o[dd] += tv[k] * sW[k * HID + dd];
        if (do_relu)
#pragma unroll
            for (int dd = 0; dd < HID; ++dd) o[dd] = fmaxf(o[dd], 0.f);
        float4* op = (float4*)(out + (size_t)i * HS);
        op[0] = make_float4(o[0], o[1], o[2], o[3]);
        op[1] = make_float4(o[4], o[5], 0.f, 0.f);
    }
}

// ===========================================================================
// tier D fallback: atomic edge pass + node update (padded layouts)
// ===========================================================================
__global__ void edge_kernel(const float* __restrict__ h, const float* __restrict__ edge_attr,
                            const int* __restrict__ src, const int* __restrict__ dst,
                            float* __restrict__ agg, int E) {
    long e = (long)blockIdx.x * blockDim.x + threadIdx.x;
    if (e >= E) return;
    int s = src[e], d = dst[e];
    const float2* ea = (const float2*)(edge_attr + (size_t)e * HID);
    float4 g0 = *(const float4*)(h + (size_t)s * HS);
    float4 g1 = *(const float4*)(h + (size_t)s * HS + 4);
    float2 a0 = ea[0], a1 = ea[1], a2 = ea[2];
    float* ag = agg + (size_t)d * HID;
    atomicAdd(ag + 0, fmaxf(g0.x + a0.x, 0.f));
    atomicAdd(ag + 1, fmaxf(g0.y + a0.y, 0.f));
    atomicAdd(ag + 2, fmaxf(g0.z + a1.x, 0.f));
    atomicAdd(ag + 3, fmaxf(g0.w + a1.y, 0.f));
    atomicAdd(ag + 4, fmaxf(g1.x + a2.x, 0.f));
    atomicAdd(ag + 5, fmaxf(g1.y + a2.y, 0.f));
}

__global__ void node_kernel(const float* __restrict__ h, const float* __restrict__ agg,
                            const float* __restrict__ W, const float* __restrict__ b,
                            float* __restrict__ out, int N, int do_relu) {
    __shared__ float sW[HID * HID];
    __shared__ float sb[HID];
    if (threadIdx.x < HID * HID) sW[threadIdx.x] = W[threadIdx.x];
    if (threadIdx.x < HID) sb[threadIdx.x] = b[threadIdx.x];
    __syncthreads();
    int i = blockIdx.x * blockDim.x + threadIdx.x;
    if (i >= N) return;
    float4 h0 = *(const float4*)(h + (size_t)i * HS);
    float4 h1 = *(const float4*)(h + (size_t)i * HS + 4);
    const float2* ap = (const float2*)(agg + (size_t)i * HID);
    float2 g0 = ap[0], g1 = ap[1], g2 = ap[2];
    float tv[HID];
    tv[0] = h0.x + g0.x; tv[1] = h0.y + g0.y;
    tv[2] = h0.z + g1.x; tv[3] = h0.w + g1.y;
    tv[4] = h1.x + g2.x; tv[5] = h1.y + g2.y;
    float o[HID];
#pragma unroll
    for (int d = 0; d < HID; ++d) o[d] = sb[d];
#pragma unroll
    for (int k = 0; k < HID; ++k)
#pragma unroll
        for (int d = 0; d < HID; ++d) o[d] += tv[k] * sW[k * HID + d];
    if (do_relu)
#pragma unroll
        for (int d = 0; d < HID; ++d) o[d] = fmaxf(o[d], 0.f);
    float4* op = (float4*)(out + (size_t)i * HS);
    op[0] = make_float4(o[0], o[1], o[2], o[3]);
    op[1] = make_float4(o[4], o[5], 0.f, 0.f);
}

// ===========================================================================
// pool + output (padded h)
// ===========================================================================
__global__ void pool_kernel(const float* __restrict__ h, const int* __restrict__ batch,
                            float* __restrict__ sums, float* __restrict__ cnts, int N) {
    int i = blockIdx.x * blockDim.x + threadIdx.x;
    int lane = threadIdx.x & 63;
    bool active = (i < N);
    float v[HID];
    int g = -1;
    if (active) {
        g = batch[i];
        float4 h0 = *(const float4*)(h + (size_t)i * HS);
        float4 h1 = *(const float4*)(h + (size_t)i * HS + 4);
        v[0] = h0.x; v[1] = h0.y; v[2] = h0.z; v[3] = h0.w; v[4] = h1.x; v[5] = h1.y;
    } else {
#pragma unroll
        for (int d = 0; d < HID; ++d) v[d] = 0.0f;
    }
    int g0 = __shfl(g, 0);
    bool uniform = __all(active) && __all(g == g0);
    if (uniform) {
#pragma unroll
        for (int d = 0; d < HID; ++d) {
            float s = v[d];
            for (int off = 32; off > 0; off >>= 1) s += __shfl_down(s, off);
            if (lane == 0) atomicAdd(&sums[(size_t)g0 * HID + d], s);
        }
        if (lane == 0) atomicAdd(&cnts[g0], 64.0f);
    } else if (active) {
#pragma unroll
        for (int d = 0; d < HID; ++d) atomicAdd(&sums[(size_t)g * HID + d], v[d]);
        atomicAdd(&cnts[g], 1.0f);
    }
}

__global__ void out_kernel(const float* __restrict__ sums, const float* __restrict__ cnts,
                           const float* __restrict__ Wl, const float* __restrict__ bl,
                           float* __restrict__ out) {
    int gI = blockIdx.x * blockDim.x + threadIdx.x;
    if (gI >= NUM_GRAPHS) return;
    float c = fmaxf(cnts[gI], 1.0f);
    float acc = bl[0];
#pragma unroll
    for (int d = 0; d < HID; ++d) acc += (sums[(size_t)gI * HID + d] / c) * Wl[d];
    out[gI] = acc;
}

// ===========================================================================
extern "C" void kernel_launch(void* const* d_in, const int* in_sizes, int n_in,
                              void* d_out, int out_size, void* d_ws, size_t ws_size,
                              hipStream_t stream) {
    const float* x         = (const float*)d_in[0];
    const int*   eidx      = (const int*)d_in[1];
    const float* edge_attr = (const float*)d_in[2];
    const int*   batch     = (const int*)d_in[3];
    const float* W1 = (const float*)d_in[4];
    const float* b1 = (const float*)d_in[5];
    const float* W2 = (const float*)d_in[6];
    const float* b2 = (const float*)d_in[7];
    const float* W3 = (const float*)d_in[8];
    const float* b3 = (const float*)d_in[9];
    const float* Wl = (const float*)d_in[10];
    const float* bl = (const float*)d_in[11];

    const int N = in_sizes[0] / HID;
    const int E = in_sizes[1] / 2;
    const int* src = eidx;
    const int* dst = eidx + E;

    const int TB = 256;
    const int nbl = (N + TB - 1) / TB;
    const int ebl = (E + TB - 1) / TB;
    const int p1bl = (E + P1_CHUNK - 1) / P1_CHUNK;

    const int NB  = (N + BNODES - 1) >> BSHIFT;           // buckets
    const int cap = ((E / (NB > 0 ? NB : 1)) + 3072 + 1023) & ~1023;
    const long slots = (long)NB * cap + 4096;             // + safety pad

    char* w = (char*)d_ws;
    size_t off = 0;
    auto alloc = [&](size_t bytes) { void* p = w + off; off += (bytes + 255) & ~(size_t)255; return p; };

    float* hX   = (float*)alloc((size_t)N * HS * sizeof(float));   // 32MB
    float* hA   = (float*)alloc((size_t)N * HS * sizeof(float));   // 32MB
    float* hB   = (float*)alloc((size_t)N * HS * sizeof(float));   // 32MB
    float* sums = (float*)alloc((size_t)NUM_GRAPHS * HID * sizeof(float));
    float* cnts = (float*)alloc((size_t)NUM_GRAPHS * sizeof(float));
    size_t tierDneed = off + (size_t)N * HID * sizeof(float);      // + agg

    uint4* packed_perm = (uint4*)alloc((size_t)slots * sizeof(uint4));  // ~245MB
    int*   gcursor     = (int*)alloc((size_t)NB * sizeof(int));
    size_t tierAneed = off;

    pad_kernel<<<nbl, TB, 0, stream>>>(x, hX, N);

    if (NB <= MAXNB && N < (1 << 20) && ws_size >= tierAneed) {
        // ---- one-time binning: coalesced reads AND writes (LDS permute) ----
        init_gcursor_kernel<<<(NB + TB - 1) / TB, TB, 0, stream>>>(gcursor, NB, cap);
        pass1_kernel<<<p1bl, TB, 0, stream>>>(src, dst, edge_attr, gcursor,
                                              packed_perm, E, cap, NB);

        // ---- bucket-fused layers ----
        layer_kernel<<<NB, TB, 0, stream>>>(hX, packed_perm, gcursor, W1, b1, hA, N, cap, 1);
        layer_kernel<<<NB, TB, 0, stream>>>(hA, packed_perm, gcursor, W2, b2, hB, N, cap, 1);
        layer_kernel<<<NB, TB, 0, stream>>>(hB, packed_perm, gcursor, W3, b3, hA, N, cap, 0);
    } else {
        // ---- tier D: atomic fallback ----
        float* agg = (float*)((char*)w + tierDneed - (size_t)N * HID * sizeof(float));
        const size_t szAgg = (size_t)N * HID * sizeof(float);
        hipMemsetAsync(agg, 0, szAgg, stream);
        edge_kernel<<<ebl, TB, 0, stream>>>(hX, edge_attr, src, dst, agg, E);
        node_kernel<<<nbl, TB, 0, stream>>>(hX, agg, W1, b1, hA, N, 1);
        hipMemsetAsync(agg, 0, szAgg, stream);
        edge_kernel<<<ebl, TB, 0, stream>>>(hA, edge_attr, src, dst, agg, E);
        node_kernel<<<nbl, TB, 0, stream>>>(hA, agg, W2, b2, hB, N, 1);
        hipMemsetAsync(agg, 0, szAgg, stream);
        edge_kernel<<<ebl, TB, 0, stream>>>(hB, edge_attr, src, dst, agg, E);
        node_kernel<<<nbl, TB, 0, stream>>>(hB, agg, W3, b3, hA, N, 0);
    }

    hipMemsetAsync(sums, 0, (size_t)NUM_GRAPHS * HID * sizeof(float), stream);
    hipMemsetAsync(cnts, 0, (size_t)NUM_GRAPHS * sizeof(float), stream);
    pool_kernel<<<nbl, TB, 0, stream>>>(hA, batch, sums, cnts, N);
    out_kernel<<<(NUM_GRAPHS + TB - 1) / TB, TB, 0, stream>>>(sums, cnts, Wl, bl, (float*)d_out);
}

// Round 11
// 1409.061 us; speedup vs baseline: 1.1009x; 1.1009x over previous
//
#include <hip/hip_runtime.h>
#include <hip/hip_fp16.h>

#define HID 6
#define HS  8                   // padded row stride (floats) for h buffers
#define NUM_GRAPHS 1000
#define BSHIFT 11
#define BNODES (1 << BSHIFT)    // 2048 nodes per bucket
#define MAXNB 512               // max buckets
#define P1_CHUNK 3072
#define P1_PERT  12             // P1_CHUNK / 256
#define LTB 1024                // layer block threads

__device__ __forceinline__ unsigned pk2(float a, float b) {
    __half2 h = __floats2half2_rn(a, b);
    return *(unsigned*)&h;
}
__device__ __forceinline__ float2 up2(unsigned u) {
    __half2 h = *(__half2*)&u;
    return __half22float2(h);
}

// nontemporal 16B load of a packed record (two 8B integer NT loads)
__device__ __forceinline__ uint4 ldnt16(const uint4* p) {
    const unsigned long long* q = (const unsigned long long*)p;
    unsigned long long lo = __builtin_nontemporal_load(q);
    unsigned long long hi = __builtin_nontemporal_load(q + 1);
    uint4 r;
    r.x = (unsigned)lo; r.y = (unsigned)(lo >> 32);
    r.z = (unsigned)hi; r.w = (unsigned)(hi >> 32);
    return r;
}

// ===========================================================================
// pad x (N x 6) -> hX (N x 8)
// ===========================================================================
__global__ void pad_kernel(const float* __restrict__ x, float* __restrict__ hX, int N) {
    int i = blockIdx.x * blockDim.x + threadIdx.x;
    if (i >= N) return;
    const float2* s = (const float2*)(x + (size_t)i * HID);
    float2 a = s[0], b = s[1], c = s[2];
    float4* o = (float4*)(hX + (size_t)i * HS);
    o[0] = make_float4(a.x, a.y, b.x, b.y);
    o[1] = make_float4(c.x, c.y, 0.f, 0.f);
}

__global__ void init_gcursor_kernel(int* __restrict__ gcursor, int NB, int cap) {
    int b = blockIdx.x * blockDim.x + threadIdx.x;
    if (b < NB) gcursor[b] = b * cap;
}

// ===========================================================================
// pass1 (r8-proven): bin edges by dst>>BSHIFT into fixed-capacity regions.
// Coalesced reads AND writes via LDS permute of 16B packed fp16 records.
// ===========================================================================
__global__ void __launch_bounds__(256) pass1_kernel(
        const int* __restrict__ src, const int* __restrict__ dst,
        const float* __restrict__ ea,
        int* __restrict__ gcursor,
        uint4* __restrict__ packed_perm,
        int E, int cap, int NB) {
    __shared__ uint4 pay[P1_CHUNK];                  // 48 KB
    __shared__ unsigned short sb_[P1_CHUNK];         // 6 KB
    __shared__ int hist[MAXNB];
    __shared__ int cnt[MAXNB];
    __shared__ int base[MAXNB];
    __shared__ int lofs[MAXNB];
    __shared__ int pairs[256];

    int t = threadIdx.x;
    long e0 = (long)blockIdx.x * P1_CHUNK;
    long rem = (long)E - e0;
    int count = (int)(rem < P1_CHUNK ? rem : P1_CHUNK);

    for (int b = t; b < MAXNB; b += 256) { hist[b] = 0; cnt[b] = 0; }
    __syncthreads();

    // phase 1: histogram (dst kept in registers)
    int d[P1_PERT];
#pragma unroll
    for (int j = 0; j < P1_PERT; ++j) {
        int le = t + j * 256;
        d[j] = (le < count) ? dst[e0 + le] : -1;
        if (d[j] >= 0) atomicAdd(&hist[d[j] >> BSHIFT], 1);
    }
    __syncthreads();

    // phase 2a: exclusive scan of hist[0..512) -> lofs
    {
        int b0 = 2 * t, b1 = 2 * t + 1;
        int s0 = hist[b0], s1 = hist[b1];
        pairs[t] = s0 + s1;
        __syncthreads();
        for (int off = 1; off < 256; off <<= 1) {
            int a = (t >= off) ? pairs[t - off] : 0;
            __syncthreads();
            pairs[t] += a;
            __syncthreads();
        }
        int excl = (t == 0) ? 0 : pairs[t - 1];
        lofs[b0] = excl;
        lofs[b1] = excl + s0;
    }
    // phase 2b: reserve global space per touched bucket
    for (int b = t; b < NB; b += 256) {
        int c = hist[b];
        base[b] = c ? atomicAdd(&gcursor[b], c) : 0;
    }
    __syncthreads();

    // phase 3: coalesced payload read -> pack fp16 -> LDS scatter at slot
#pragma unroll
    for (int j = 0; j < P1_PERT; ++j) {
        int le = t + j * 256;
        if (le >= count) continue;
        int dd = d[j];
        int b = dd >> BSHIFT;
        long e = e0 + le;
        int s = src[e];
        const float2* ep = (const float2*)(ea + (size_t)e * HID);
        float2 A = ep[0], B = ep[1], C = ep[2];
        uint4 p;
        p.x = pk2(A.x, A.y);
        p.y = pk2(B.x, B.y);
        p.z = pk2(C.x, C.y);
        p.w = (unsigned)s | ((unsigned)(dd & (BNODES - 1)) << 20);
        int r = atomicAdd(&cnt[b], 1);
        int slot = lofs[b] + r;
        pay[slot] = p;
        sb_[slot] = (unsigned short)b;
    }
    __syncthreads();

    // phase 4: sequential LDS read -> contiguous global runs
    for (int s2 = t; s2 < count; s2 += 256) {
        int b = sb_[s2];
        long gpos = (long)base[b] + (s2 - lofs[b]);
        packed_perm[gpos] = pay[s2];
    }
}

// ===========================================================================
// shared edge-aggregation body (LDS sagg), 4x batched, NT packed loads
// ===========================================================================
#define EDGE_UPD(P, G0, G1)                                                   \
    do {                                                                      \
        int dl_ = (P.w >> 20) & (BNODES - 1);                                 \
        float2 e01 = up2(P.x), e23 = up2(P.y), e45 = up2(P.z);                \
        float* pp = sagg + (size_t)dl_ * HID;                                 \
        atomicAdd(pp + 0, fmaxf(G0.x + e01.x, 0.f));                          \
        atomicAdd(pp + 1, fmaxf(G0.y + e01.y, 0.f));                          \
        atomicAdd(pp + 2, fmaxf(G0.z + e23.x, 0.f));                          \
        atomicAdd(pp + 3, fmaxf(G0.w + e23.y, 0.f));                          \
        atomicAdd(pp + 4, fmaxf(G1.x + e45.x, 0.f));                          \
        atomicAdd(pp + 5, fmaxf(G1.y + e45.y, 0.f));                          \
    } while (0)

__device__ __forceinline__ void agg_edges(float* sagg, const float* __restrict__ h,
                                          const uint4* __restrict__ packed,
                                          long kbeg, int cnt, int t) {
    int k4 = cnt & ~(4 * LTB - 1);
    for (int k = t; k < k4; k += 4 * LTB) {
        uint4 p0 = ldnt16(packed + kbeg + k);
        uint4 p1 = ldnt16(packed + kbeg + k + LTB);
        uint4 p2 = ldnt16(packed + kbeg + k + 2 * LTB);
        uint4 p3 = ldnt16(packed + kbeg + k + 3 * LTB);
        int s0 = p0.w & 0xFFFFF, s1 = p1.w & 0xFFFFF;
        int s2 = p2.w & 0xFFFFF, s3 = p3.w & 0xFFFFF;
        float4 a0 = *(const float4*)(h + (size_t)s0 * HS);
        float4 b0 = *(const float4*)(h + (size_t)s0 * HS + 4);
        float4 a1 = *(const float4*)(h + (size_t)s1 * HS);
        float4 b1 = *(const float4*)(h + (size_t)s1 * HS + 4);
        float4 a2 = *(const float4*)(h + (size_t)s2 * HS);
        float4 b2 = *(const float4*)(h + (size_t)s2 * HS + 4);
        float4 a3 = *(const float4*)(h + (size_t)s3 * HS);
        float4 b3 = *(const float4*)(h + (size_t)s3 * HS + 4);
        EDGE_UPD(p0, a0, b0);
        EDGE_UPD(p1, a1, b1);
        EDGE_UPD(p2, a2, b2);
        EDGE_UPD(p3, a3, b3);
    }
    for (int k = k4 + t; k < cnt; k += LTB) {
        uint4 p = ldnt16(packed + kbeg + k);
        int s = p.w & 0xFFFFF;
        float4 g0 = *(const float4*)(h + (size_t)s * HS);
        float4 g1 = *(const float4*)(h + (size_t)s * HS + 4);
        EDGE_UPD(p, g0, g1);
    }
}

// ===========================================================================
// bucket-fused GINE layer (layers 1,2): 1024 threads, writes h_out
// ===========================================================================
__global__ void __launch_bounds__(LTB) layer_kernel(
        const float* __restrict__ h,
        const uint4* __restrict__ packed,
        const int* __restrict__ gcursor,
        const float* __restrict__ W, const float* __restrict__ b,
        float* __restrict__ out, int N, int cap) {
    __shared__ float sagg[BNODES * HID];     // 48 KB
    __shared__ float sW[HID * HID];
    __shared__ float sb[HID];
    int t = threadIdx.x;
    int bk = blockIdx.x;
    if (t < HID * HID) sW[t] = W[t];
    if (t < HID) sb[t] = b[t];
    for (int i = t; i < BNODES * HID; i += LTB) sagg[i] = 0.f;
    __syncthreads();

    long kbeg = (long)bk * cap;
    int cnt = gcursor[bk] - (int)kbeg;
    agg_edges(sagg, h, packed, kbeg, cnt, t);
    __syncthreads();

    int nodeBase = bk << BSHIFT;
#pragma unroll
    for (int n = t; n < BNODES; n += LTB) {
        int i = nodeBase + n;
        if (i >= N) break;
        float4 h0 = *(const float4*)(h + (size_t)i * HS);
        float4 h1 = *(const float4*)(h + (size_t)i * HS + 4);
        const float* sp = sagg + (size_t)n * HID;
        float tv[HID];
        tv[0] = h0.x + sp[0]; tv[1] = h0.y + sp[1]; tv[2] = h0.z + sp[2];
        tv[3] = h0.w + sp[3]; tv[4] = h1.x + sp[4]; tv[5] = h1.y + sp[5];
        float o[HID];
#pragma unroll
        for (int dd = 0; dd < HID; ++dd) o[dd] = sb[dd];
#pragma unroll
        for (int k = 0; k < HID; ++k)
#pragma unroll
            for (int dd = 0; dd < HID; ++dd) o[dd] += tv[k] * sW[k * HID + dd];
#pragma unroll
        for (int dd = 0; dd < HID; ++dd) o[dd] = fmaxf(o[dd], 0.f);   // relu
        float4* op = (float4*)(out + (size_t)i * HS);
        op[0] = make_float4(o[0], o[1], o[2], o[3]);
        op[1] = make_float4(o[4], o[5], 0.f, 0.f);
    }
}

// ===========================================================================
// layer 3 fused with mean-pool accumulation: never writes h
// ===========================================================================
__global__ void __launch_bounds__(LTB) layer3_pool_kernel(
        const float* __restrict__ h,
        const uint4* __restrict__ packed,
        const int* __restrict__ gcursor,
        const float* __restrict__ W, const float* __restrict__ b,
        const int* __restrict__ batch,
        float* __restrict__ sums, float* __restrict__ cnts,
        int N, int cap) {
    __shared__ float sagg[BNODES * HID];     // 48 KB
    __shared__ float sW[HID * HID];
    __shared__ float sb[HID];
    int t = threadIdx.x;
    int bk = blockIdx.x;
    if (t < HID * HID) sW[t] = W[t];
    if (t < HID) sb[t] = b[t];
    for (int i = t; i < BNODES * HID; i += LTB) sagg[i] = 0.f;
    __syncthreads();

    long kbeg = (long)bk * cap;
    int cnt = gcursor[bk] - (int)kbeg;
    agg_edges(sagg, h, packed, kbeg, cnt, t);
    __syncthreads();

    int nodeBase = bk << BSHIFT;
    int lane = t & 63;
#pragma unroll
    for (int n = t; n < BNODES; n += LTB) {
        int i = nodeBase + n;
        bool active = (i < N);
        float o[HID];
        int g = -1;
        if (active) {
            float4 h0 = *(const float4*)(h + (size_t)i * HS);
            float4 h1 = *(const float4*)(h + (size_t)i * HS + 4);
            const float* sp = sagg + (size_t)n * HID;
            float tv[HID];
            tv[0] = h0.x + sp[0]; tv[1] = h0.y + sp[1]; tv[2] = h0.z + sp[2];
            tv[3] = h0.w + sp[3]; tv[4] = h1.x + sp[4]; tv[5] = h1.y + sp[5];
#pragma unroll
            for (int dd = 0; dd < HID; ++dd) o[dd] = sb[dd];
#pragma unroll
            for (int k = 0; k < HID; ++k)
#pragma unroll
                for (int dd = 0; dd < HID; ++dd) o[dd] += tv[k] * sW[k * HID + dd];
            g = batch[i];
        } else {
#pragma unroll
            for (int dd = 0; dd < HID; ++dd) o[dd] = 0.f;
        }
        int g0 = __shfl(g, 0);
        bool uniform = __all(active) && __all(g == g0);
        if (uniform) {
#pragma unroll
            for (int dd = 0; dd < HID; ++dd) {
                float s = o[dd];
                for (int off2 = 32; off2 > 0; off2 >>= 1) s += __shfl_down(s, off2);
                if (lane == 0) atomicAdd(&sums[(size_t)g0 * HID + dd], s);
            }
            if (lane == 0) atomicAdd(&cnts[g0], 64.0f);
        } else if (active) {
#pragma unroll
            for (int dd = 0; dd < HID; ++dd) atomicAdd(&sums[(size_t)g * HID + dd], o[dd]);
            atomicAdd(&cnts[g], 1.0f);
        }
    }
}

// ===========================================================================
// tier D fallback: atomic edge pass + node update (padded layouts)
// ===========================================================================
__global__ void edge_kernel(const float* __restrict__ h, const float* __restrict__ edge_attr,
                            const int* __restrict__ src, const int* __restrict__ dst,
                            float* __restrict__ agg, int E) {
    long e = (long)blockIdx.x * blockDim.x + threadIdx.x;
    if (e >= E) return;
    int s = src[e], d = dst[e];
    const float2* ea = (const float2*)(edge_attr + (size_t)e * HID);
    float4 g0 = *(const float4*)(h + (size_t)s * HS);
    float4 g1 = *(const float4*)(h + (size_t)s * HS + 4);
    float2 a0 = ea[0], a1 = ea[1], a2 = ea[2];
    float* ag = agg + (size_t)d * HID;
    atomicAdd(ag + 0, fmaxf(g0.x + a0.x, 0.f));
    atomicAdd(ag + 1, fmaxf(g0.y + a0.y, 0.f));
    atomicAdd(ag + 2, fmaxf(g0.z + a1.x, 0.f));
    atomicAdd(ag + 3, fmaxf(g0.w + a1.y, 0.f));
    atomicAdd(ag + 4, fmaxf(g1.x + a2.x, 0.f));
    atomicAdd(ag + 5, fmaxf(g1.y + a2.y, 0.f));
}

__global__ void node_kernel(const float* __restrict__ h, const float* __restrict__ agg,
                            const float* __restrict__ W, const float* __restrict__ b,
                            float* __restrict__ out, int N, int do_relu) {
    __shared__ float sW[HID * HID];
    __shared__ float sb[HID];
    if (threadIdx.x < HID * HID) sW[threadIdx.x] = W[threadIdx.x];
    if (threadIdx.x < HID) sb[threadIdx.x] = b[threadIdx.x];
    __syncthreads();
    int i = blockIdx.x * blockDim.x + threadIdx.x;
    if (i >= N) return;
    float4 h0 = *(const float4*)(h + (size_t)i * HS);
    float4 h1 = *(const float4*)(h + (size_t)i * HS + 4);
    const float2* ap = (const float2*)(agg + (size_t)i * HID);
    float2 g0 = ap[0], g1 = ap[1], g2 = ap[2];
    float tv[HID];
    tv[0] = h0.x + g0.x; tv[1] = h0.y + g0.y;
    tv[2] = h0.z + g1.x; tv[3] = h0.w + g1.y;
    tv[4] = h1.x + g2.x; tv[5] = h1.y + g2.y;
    float o[HID];
#pragma unroll
    for (int d = 0; d < HID; ++d) o[d] = sb[d];
#pragma unroll
    for (int k = 0; k < HID; ++k)
#pragma unroll
        for (int d = 0; d < HID; ++d) o[d] += tv[k] * sW[k * HID + d];
    if (do_relu)
#pragma unroll
        for (int d = 0; d < HID; ++d) o[d] = fmaxf(o[d], 0.f);
    float4* op = (float4*)(out + (size_t)i * HS);
    op[0] = make_float4(o[0], o[1], o[2], o[3]);
    op[1] = make_float4(o[4], o[5], 0.f, 0.f);
}

// ===========================================================================
// standalone pool (fallback path) + output
// ===========================================================================
__global__ void pool_kernel(const float* __restrict__ h, const int* __restrict__ batch,
                            float* __restrict__ sums, float* __restrict__ cnts, int N) {
    int i = blockIdx.x * blockDim.x + threadIdx.x;
    int lane = threadIdx.x & 63;
    bool active = (i < N);
    float v[HID];
    int g = -1;
    if (active) {
        g = batch[i];
        float4 h0 = *(const float4*)(h + (size_t)i * HS);
        float4 h1 = *(const float4*)(h + (size_t)i * HS + 4);
        v[0] = h0.x; v[1] = h0.y; v[2] = h0.z; v[3] = h0.w; v[4] = h1.x; v[5] = h1.y;
    } else {
#pragma unroll
        for (int d = 0; d < HID; ++d) v[d] = 0.0f;
    }
    int g0 = __shfl(g, 0);
    bool uniform = __all(active) && __all(g == g0);
    if (uniform) {
#pragma unroll
        for (int d = 0; d < HID; ++d) {
            float s = v[d];
            for (int off = 32; off > 0; off >>= 1) s += __shfl_down(s, off);
            if (lane == 0) atomicAdd(&sums[(size_t)g0 * HID + d], s);
        }
        if (lane == 0) atomicAdd(&cnts[g0], 64.0f);
    } else if (active) {
#pragma unroll
        for (int d = 0; d < HID; ++d) atomicAdd(&sums[(size_t)g * HID + d], v[d]);
        atomicAdd(&cnts[g], 1.0f);
    }
}

__global__ void out_kernel(const float* __restrict__ sums, const float* __restrict__ cnts,
                           const float* __restrict__ Wl, const float* __restrict__ bl,
                           float* __restrict__ out) {
    int gI = blockIdx.x * blockDim.x + threadIdx.x;
    if (gI >= NUM_GRAPHS) return;
    float c = fmaxf(cnts[gI], 1.0f);
    float acc = bl[0];
#pragma unroll
    for (int d = 0; d < HID; ++d) acc += (sums[(size_t)gI * HID + d] / c) * Wl[d];
    out[gI] = acc;
}

// ===========================================================================
extern "C" void kernel_launch(void* const* d_in, const int* in_sizes, int n_in,
                              void* d_out, int out_size, void* d_ws, size_t ws_size,
                              hipStream_t stream) {
    const float* x         = (const float*)d_in[0];
    const int*   eidx      = (const int*)d_in[1];
    const float* edge_attr = (const float*)d_in[2];
    const int*   batch     = (const int*)d_in[3];
    const float* W1 = (const float*)d_in[4];
    const float* b1 = (const float*)d_in[5];
    const float* W2 = (const float*)d_in[6];
    const float* b2 = (const float*)d_in[7];
    const float* W3 = (const float*)d_in[8];
    const float* b3 = (const float*)d_in[9];
    const float* Wl = (const float*)d_in[10];
    const float* bl = (const float*)d_in[11];

    const int N = in_sizes[0] / HID;
    const int E = in_sizes[1] / 2;
    const int* src = eidx;
    const int* dst = eidx + E;

    const int TB = 256;
    const int nbl = (N + TB - 1) / TB;
    const int ebl = (E + TB - 1) / TB;
    const int p1bl = (E + P1_CHUNK - 1) / P1_CHUNK;

    const int NB  = (N + BNODES - 1) >> BSHIFT;           // buckets (489)
    const int cap = ((E / (NB > 0 ? NB : 1)) + 3072 + 1023) & ~1023;
    const long slots = (long)NB * cap + 4096;             // + safety pad

    char* w = (char*)d_ws;
    size_t off = 0;
    auto alloc = [&](size_t bytes) { void* p = w + off; off += (bytes + 255) & ~(size_t)255; return p; };

    float* hX   = (float*)alloc((size_t)N * HS * sizeof(float));   // 32MB
    float* hA   = (float*)alloc((size_t)N * HS * sizeof(float));   // 32MB
    float* hB   = (float*)alloc((size_t)N * HS * sizeof(float));   // 32MB
    float* sums = (float*)alloc((size_t)NUM_GRAPHS * HID * sizeof(float));
    float* cnts = (float*)alloc((size_t)NUM_GRAPHS * sizeof(float));
    size_t tierDneed = off + (size_t)N * HID * sizeof(float);      // + agg

    uint4* packed_perm = (uint4*)alloc((size_t)slots * sizeof(uint4));  // ~225MB
    int*   gcursor     = (int*)alloc((size_t)NB * sizeof(int));
    size_t tierAneed = off;

    pad_kernel<<<nbl, TB, 0, stream>>>(x, hX, N);
    hipMemsetAsync(sums, 0, (size_t)NUM_GRAPHS * HID * sizeof(float), stream);
    hipMemsetAsync(cnts, 0, (size_t)NUM_GRAPHS * sizeof(float), stream);

    if (NB <= MAXNB && N < (1 << 20) && ws_size >= tierAneed) {
        // ---- one-time binning: coalesced reads AND writes (LDS permute) ----
        init_gcursor_kernel<<<(NB + TB - 1) / TB, TB, 0, stream>>>(gcursor, NB, cap);
        pass1_kernel<<<p1bl, TB, 0, stream>>>(src, dst, edge_attr, gcursor,
                                              packed_perm, E, cap, NB);

        // ---- bucket-fused layers, 1024-thread blocks (2 blocks/CU = 32 w/CU) ----
        layer_kernel<<<NB, LTB, 0, stream>>>(hX, packed_perm, gcursor, W1, b1, hA, N, cap);
        layer_kernel<<<NB, LTB, 0, stream>>>(hA, packed_perm, gcursor, W2, b2, hB, N, cap);
        layer3_pool_kernel<<<NB, LTB, 0, stream>>>(hB, packed_perm, gcursor, W3, b3,
                                                   batch, sums, cnts, N, cap);
    } else {
        // ---- tier D: atomic fallback ----
        float* agg = (float*)((char*)w + tierDneed - (size_t)N * HID * sizeof(float));
        const size_t szAgg = (size_t)N * HID * sizeof(float);
        hipMemsetAsync(agg, 0, szAgg, stream);
        edge_kernel<<<ebl, TB, 0, stream>>>(hX, edge_attr, src, dst, agg, E);
        node_kernel<<<nbl, TB, 0, stream>>>(hX, agg, W1, b1, hA, N, 1);
        hipMemsetAsync(agg, 0, szAgg, stream);
        edge_kernel<<<ebl, TB, 0, stream>>>(hA, edge_attr, src, dst, agg, E);
        node_kernel<<<nbl, TB, 0, stream>>>(hA, agg, W2, b2, hB, N, 1);
        hipMemsetAsync(agg, 0, szAgg, stream);
        edge_kernel<<<ebl, TB, 0, stream>>>(hB, edge_attr, src, dst, agg, E);
        node_kernel<<<nbl, TB, 0, stream>>>(hB, agg, W3, b3, hA, N, 0);
        pool_kernel<<<nbl, TB, 0, stream>>>(hA, batch, sums, cnts, N);
    }

    out_kernel<<<(NUM_GRAPHS + TB - 1) / TB, TB, 0, stream>>>(sums, cnts, Wl, bl, (float*)d_out);
}